// Round 2
// 1211.809 us; speedup vs baseline: 1.4074x; 1.4074x over previous
//
#include <hip/hip_runtime.h>
#include <hip/hip_bf16.h>
#include <cstdint>
#include <cstddef>
#include <type_traits>

#define TPB 256

typedef __attribute__((ext_vector_type(8))) short short8;
typedef __attribute__((ext_vector_type(4))) float floatx4;

__device__ __forceinline__ float bfbits2f(short v) {
    union { unsigned u; float f; } t;
    t.u = ((unsigned)(unsigned short)v) << 16;
    return t.f;
}

__device__ __forceinline__ void store_c(float* C, size_t off, float v) { C[off] = v; }
__device__ __forceinline__ void store_c(__hip_bfloat16* C, size_t off, float v) { C[off] = __float2bfloat16(v); }

// async global->LDS, 16B per lane. Dest must be wave-uniform base + lane*16.
__device__ __forceinline__ void gload16(const __hip_bfloat16* g, __hip_bfloat16* l) {
    __builtin_amdgcn_global_load_lds(
        (const __attribute__((address_space(1))) void*)g,
        (__attribute__((address_space(3))) void*)l, 16, 0, 0);
}

// VALU-staged fp32 chunk: load 8 fp32 (guarded), convert, write to swizzled slot.
// Slot c (0..511) of a 128x32 bf16 tile holds global chunk q=(c&3)^((r>>1)&3)
// of row r=c>>2 (same layout the async path produces via pre-swizzled source).
template<bool ROWG>
__device__ __forceinline__ void stage_cvt(const float* __restrict__ Msrc, long ld,
                                          long rowlim, int klim,
                                          long tilebase, int k0,
                                          __hip_bfloat16* Ls, int c)
{
    const int r = c >> 2;
    const int q = (c & 3) ^ ((r >> 1) & 3);
    const long gr = tilebase + r;
    const int gc = k0 + q * 8;
    union { __hip_bfloat16 h[8]; uint4 u4; } t;
    const bool rowok = !ROWG || (gr < rowlim);
    if (rowok && gc + 8 <= klim) {
        const float* s = Msrc + gr * ld + gc;
        const float4 v0 = *(const float4*)s;
        const float4 v1 = *(const float4*)(s + 4);
        t.h[0] = __float2bfloat16(v0.x); t.h[1] = __float2bfloat16(v0.y);
        t.h[2] = __float2bfloat16(v0.z); t.h[3] = __float2bfloat16(v0.w);
        t.h[4] = __float2bfloat16(v1.x); t.h[5] = __float2bfloat16(v1.y);
        t.h[6] = __float2bfloat16(v1.z); t.h[7] = __float2bfloat16(v1.w);
    } else {
#pragma unroll
        for (int e = 0; e < 8; ++e) {
            const float v = (rowok && (gc + e) < klim) ? Msrc[gr * ld + gc + e] : 0.f;
            t.h[e] = __float2bfloat16(v);
        }
    }
    *(uint4*)(&Ls[c * 8]) = t.u4;
}

// ---------------------------------------------------------------------------
// GEMM: C[M,N] = A[M,K] @ B[N,K]^T (+ bias[n]) (+= C if ACC).
// bf16 operand: async global_load_lds; requires rows in-bounds (M/N covered
//   exactly by grid / padded buffer), K mult of 32, ld mult of 8.
// fp32 operand: VALU-staged with K-limit guard (A) / row-limit guard (B).
// LDS layout XOR-chunk-swizzled on both write and read sides.
// ---------------------------------------------------------------------------
template<typename TA, typename TB, typename OutT, bool ACC, bool BIAS, bool NEDGE, bool SWAPGRID>
__global__ __launch_bounds__(TPB)
void gemm_bf(const TA* __restrict__ A, int lda, int Ka,
             const TB* __restrict__ Bm, int ldb, long NBrow,
             OutT* __restrict__ C, long ldc,
             const float* __restrict__ bias,
             int N, int K)
{
    constexpr bool AF32 = std::is_same<TA, float>::value;
    constexpr bool BF32 = std::is_same<TB, float>::value;

    __shared__ __align__(16) __hip_bfloat16 As[128 * 32];
    __shared__ __align__(16) __hip_bfloat16 Bs[128 * 32];

    const int tid  = threadIdx.x;
    const int lane = tid & 63;
    const int wave = tid >> 6;
    const int wm   = (wave & 1) * 64;
    const int wn   = (wave >> 1) * 64;
    const int l15  = lane & 15;
    const int quad = lane >> 4;
    const long tileM = (long)(SWAPGRID ? blockIdx.x : blockIdx.y) * 128;
    const long tileN = (long)(SWAPGRID ? blockIdx.y : blockIdx.x) * 128;

    const int c0 = tid, c1 = tid + 256;
    const int r0 = c0 >> 2, r1 = c1 >> 2;
    const int q0 = (c0 & 3) ^ ((r0 >> 1) & 3);
    const int q1 = (c1 & 3) ^ ((r1 >> 1) & 3);

    const __hip_bfloat16* a0 = nullptr; const __hip_bfloat16* a1 = nullptr;
    const __hip_bfloat16* b0 = nullptr; const __hip_bfloat16* b1 = nullptr;
    if constexpr (!AF32) {
        a0 = (const __hip_bfloat16*)A + (tileM + r0) * (long)lda + q0 * 8;
        a1 = (const __hip_bfloat16*)A + (tileM + r1) * (long)lda + q1 * 8;
    }
    if constexpr (!BF32) {
        b0 = (const __hip_bfloat16*)Bm + (tileN + r0) * (long)ldb + q0 * 8;
        b1 = (const __hip_bfloat16*)Bm + (tileN + r1) * (long)ldb + q1 * 8;
    }
    __hip_bfloat16* la0 = &As[c0 * 8];
    __hip_bfloat16* la1 = &As[c1 * 8];
    __hip_bfloat16* lb0 = &Bs[c0 * 8];
    __hip_bfloat16* lb1 = &Bs[c1 * 8];

    const int qs = quad ^ ((l15 >> 1) & 3);   // swizzled read chunk

    floatx4 acc[4][4];
#pragma unroll
    for (int i = 0; i < 4; ++i)
#pragma unroll
        for (int j = 0; j < 4; ++j)
            acc[i][j] = (floatx4){0.f, 0.f, 0.f, 0.f};

    for (int k0 = 0; k0 < K; k0 += 32) {
        // issue async loads first so they overlap any VALU staging
        if constexpr (!AF32) { gload16(a0, la0); gload16(a1, la1); a0 += 32; a1 += 32; }
        if constexpr (!BF32) { gload16(b0, lb0); gload16(b1, lb1); b0 += 32; b1 += 32; }
        if constexpr (AF32) {
            stage_cvt<false>((const float*)A, lda, 0, Ka, tileM, k0, As, c0);
            stage_cvt<false>((const float*)A, lda, 0, Ka, tileM, k0, As, c1);
        }
        if constexpr (BF32) {
            stage_cvt<true>((const float*)Bm, ldb, NBrow, K, tileN, k0, Bs, c0);
            stage_cvt<true>((const float*)Bm, ldb, NBrow, K, tileN, k0, Bs, c1);
        }
        __syncthreads();   // drains vmcnt+lgkmcnt before barrier

        short8 af[4], bfg[4];
#pragma unroll
        for (int i = 0; i < 4; ++i)
            af[i] = *(const short8*)(&As[(wm + i * 16 + l15) * 32 + qs * 8]);
#pragma unroll
        for (int j = 0; j < 4; ++j)
            bfg[j] = *(const short8*)(&Bs[(wn + j * 16 + l15) * 32 + qs * 8]);
#pragma unroll
        for (int i = 0; i < 4; ++i)
#pragma unroll
            for (int j = 0; j < 4; ++j)
                acc[i][j] = __builtin_amdgcn_mfma_f32_16x16x32_bf16(af[i], bfg[j], acc[i][j], 0, 0, 0);
        __syncthreads();
    }

#pragma unroll
    for (int i = 0; i < 4; ++i) {
#pragma unroll
        for (int j = 0; j < 4; ++j) {
            const long n = tileN + wn + j * 16 + l15;
            if (NEDGE && n >= N) continue;
            float bv = 0.f;
            if constexpr (BIAS) bv = bias[n];
#pragma unroll
            for (int r = 0; r < 4; ++r) {
                const long m = tileM + wm + i * 16 + quad * 4 + r;
                const size_t off = (size_t)(m * ldc + n);
                float v = acc[i][j][r] + bv;
                if constexpr (ACC) v += ((const float*)C)[off];
                store_c(C, off, v);
            }
        }
    }
}

// ---------------------------------------------------------------------------
// fp32 -> bf16 strided convert with zero padding outside [rows_src, cols_src)
// ---------------------------------------------------------------------------
union Bf4 { __hip_bfloat16 h[4]; uint2 u; };

__global__ __launch_bounds__(TPB)
void cvt2bf(const float* __restrict__ src, long sld,
            __hip_bfloat16* __restrict__ dst, long dld,
            int rows_dst, int cols_dst, int rows_src, int cols_src)
{
    const int idx = blockIdx.x * TPB + threadIdx.x;     // one per 4 dst cols
    const int cpr = cols_dst >> 2;
    if (idx >= rows_dst * cpr) return;
    const int r  = idx / cpr;
    const int c4 = (idx - r * cpr) << 2;
    Bf4 o;
    if (r < rows_src && c4 + 4 <= cols_src) {
        const float4 v = *(const float4*)(src + (long)r * sld + c4);
        o.h[0] = __float2bfloat16(v.x); o.h[1] = __float2bfloat16(v.y);
        o.h[2] = __float2bfloat16(v.z); o.h[3] = __float2bfloat16(v.w);
    } else {
#pragma unroll
        for (int e = 0; e < 4; ++e) {
            const float v = (r < rows_src && (c4 + e) < cols_src)
                              ? src[(long)r * sld + c4 + e] : 0.f;
            o.h[e] = __float2bfloat16(v);
        }
    }
    *(uint2*)(dst + (long)r * dld + c4) = o.u;
}

// ---------------------------------------------------------------------------
// Bahdanau attention, one batch row per block. U bf16, feats fp32.
// ---------------------------------------------------------------------------
__global__ __launch_bounds__(TPB)
void attn_kernel(const float* __restrict__ Wh,
                 const __hip_bfloat16* __restrict__ U,
                 const float* __restrict__ feats, int feats_ld,
                 const float* __restrict__ bias,
                 const float* __restrict__ w,
                 __hip_bfloat16* __restrict__ dst,
                 int dst_ld, int N, int D)
{
    const int b = blockIdx.x;
    const int tid = threadIdx.x;
    const int lane = tid & 63;
    const int wave = tid >> 6;
    __shared__ float sc[64];

    const float* whb = Wh + (size_t)b * 512;
    const int hoff = lane * 8;             // 64 lanes x 8 = 512 exactly
    float wh[8], bb[8], ww[8];
    {
        float4 t0 = *(const float4*)(whb + hoff), t1 = *(const float4*)(whb + hoff + 4);
        wh[0]=t0.x; wh[1]=t0.y; wh[2]=t0.z; wh[3]=t0.w; wh[4]=t1.x; wh[5]=t1.y; wh[6]=t1.z; wh[7]=t1.w;
        t0 = *(const float4*)(bias + hoff); t1 = *(const float4*)(bias + hoff + 4);
        bb[0]=t0.x; bb[1]=t0.y; bb[2]=t0.z; bb[3]=t0.w; bb[4]=t1.x; bb[5]=t1.y; bb[6]=t1.z; bb[7]=t1.w;
        t0 = *(const float4*)(w + hoff); t1 = *(const float4*)(w + hoff + 4);
        ww[0]=t0.x; ww[1]=t0.y; ww[2]=t0.z; ww[3]=t0.w; ww[4]=t1.x; ww[5]=t1.y; ww[6]=t1.z; ww[7]=t1.w;
    }
    for (int n = wave; n < N; n += 4) {
        const short8 u = *(const short8*)(U + ((size_t)b * N + n) * 512 + hoff);
        float s = 0.f;
#pragma unroll
        for (int e = 0; e < 8; ++e)
            s += tanhf(wh[e] + bfbits2f(u[e]) + bb[e]) * ww[e];
#pragma unroll
        for (int off = 32; off > 0; off >>= 1) s += __shfl_down(s, off);
        if (lane == 0) sc[n] = s;
    }
    __syncthreads();
    if (tid == 0) {
        float mx = -3.4e38f;
        for (int n = 0; n < N; ++n) mx = fmaxf(mx, sc[n]);
        float sum = 0.f;
        for (int n = 0; n < N; ++n) { float e = expf(sc[n] - mx); sc[n] = e; sum += e; }
        const float inv = 1.f / sum;
        for (int n = 0; n < N; ++n) sc[n] *= inv;
    }
    __syncthreads();
    for (int d = tid; d < D; d += TPB) {
        float a = 0.f;
        for (int n = 0; n < N; ++n)
            a += sc[n] * feats[((size_t)b * N + n) * feats_ld + d];
        dst[(size_t)b * dst_ld + d] = __float2bfloat16(a);
    }
}

__device__ __forceinline__ float sigmoidf_(float x) { return 1.f / (1.f + expf(-x)); }

__global__ __launch_bounds__(TPB)
void lstm_kernel(const float* __restrict__ gates,
                 const float* __restrict__ b_ih,
                 const float* __restrict__ b_hh,
                 const float* __restrict__ c0,
                 float* __restrict__ out_h,
                 float* __restrict__ out_c,
                 __hip_bfloat16* __restrict__ h_bf)
{
    const int idx = blockIdx.x * TPB + threadIdx.x;   // B*H threads
    if (idx >= 1024 * 512) return;
    const int hh = idx & 511;
    const float* g = gates + (size_t)(idx >> 9) * 2048;
    const float gi = g[hh]        + b_ih[hh]        + b_hh[hh];
    const float gf = g[512 + hh]  + b_ih[512 + hh]  + b_hh[512 + hh];
    const float gg = g[1024 + hh] + b_ih[1024 + hh] + b_hh[1024 + hh];
    const float go = g[1536 + hh] + b_ih[1536 + hh] + b_hh[1536 + hh];
    const float c = sigmoidf_(gf) * c0[idx] + sigmoidf_(gi) * tanhf(gg);
    const float h = sigmoidf_(go) * tanhf(c);
    out_h[idx] = h;
    out_c[idx] = c;
    h_bf[idx]  = __float2bfloat16(h);
}

// ---------------------------------------------------------------------------
// 2-pass log-softmax: online (max,sum) in one read, then subtract-lse pass.
// ---------------------------------------------------------------------------
__global__ __launch_bounds__(TPB)
void logsoftmax2(float* __restrict__ logits, int V)
{
    const int b = blockIdx.x;
    float* row = logits + (size_t)b * V;
    const int tid = threadIdx.x;

    const int mis  = (int)(((uintptr_t)row >> 2) & 3);
    const int head = mis ? (4 - mis) : 0;
    const int nv   = (V - head) >> 2;
    const int tail0 = head + nv * 4;

    float m = -3.4e38f, s = 0.f;
    if (tid < head) {
        const float x = row[tid];
        if (x > m) { s *= expf(m - x); m = x; }
        s += expf(x - m);
    }
    for (int k = tid; k < nv; k += TPB) {
        const float4 x = *(const float4*)(row + head + 4 * k);
        const float cm = fmaxf(fmaxf(x.x, x.y), fmaxf(x.z, x.w));
        if (cm > m) { s *= expf(m - cm); m = cm; }
        s += expf(x.x - m) + expf(x.y - m) + expf(x.z - m) + expf(x.w - m);
    }
    for (int i = tail0 + tid; i < V; i += TPB) {
        const float x = row[i];
        if (x > m) { s *= expf(m - x); m = x; }
        s += expf(x - m);
    }

    __shared__ float rm[TPB], rs[TPB];
    rm[tid] = m; rs[tid] = s; __syncthreads();
    for (int st = TPB / 2; st > 0; st >>= 1) {
        if (tid < st) {
            const float m2 = rm[tid + st], s2 = rs[tid + st];
            const float M = fmaxf(rm[tid], m2);
            rs[tid] = rs[tid] * expf(rm[tid] - M) + s2 * expf(m2 - M);
            rm[tid] = M;
        }
        __syncthreads();
    }
    const float lse = rm[0] + logf(rs[0]);

    if (tid < head) row[tid] -= lse;
    for (int k = tid; k < nv; k += TPB) {
        float4 x = *(const float4*)(row + head + 4 * k);
        x.x -= lse; x.y -= lse; x.z -= lse; x.w -= lse;
        *(float4*)(row + head + 4 * k) = x;
    }
    for (int i = tail0 + tid; i < V; i += TPB) row[i] -= lse;
}

// ---------------------------------------------------------------------------

extern "C" void kernel_launch(void* const* d_in, const int* in_sizes, int n_in,
                              void* d_out, int out_size, void* d_ws, size_t ws_size,
                              hipStream_t stream)
{
    (void)in_sizes; (void)n_in; (void)out_size; (void)ws_size;
    const int B = 1024, H = 512, S = 300, E = 512, V = 50257;
    const int NO = 36, NA = 26, NV_ = 26, NOS = 20;
    const int Sp = 320;      // S padded to multiple of 32 (K of semantic U GEMM)
    const int S3p = 928;     // 3*S=900 padded to multiple of 32

    typedef const float* cf;
    cf objects   = (cf)d_in[0];
    cf action    = (cf)d_in[1];
    cf video     = (cf)d_in[2];
    cf obj_sem   = (cf)d_in[3];
    cf act_sem   = (cf)d_in[4];
    cf vid_sem   = (cf)d_in[5];
    cf embed     = (cf)d_in[6];
    cf h0        = (cf)d_in[7];
    cf c0        = (cf)d_in[8];
    cf W_w       = (cf)d_in[9];
    cf Uo_w      = (cf)d_in[10];
    cf bo        = (cf)d_in[11];
    cf wo_w      = (cf)d_in[12];
    cf Uos_w     = (cf)d_in[13];
    cf bos       = (cf)d_in[14];
    cf wos_w     = (cf)d_in[15];
    cf Um_w      = (cf)d_in[16];
    cf bm        = (cf)d_in[17];
    cf wm_w      = (cf)d_in[18];
    cf Uv_w      = (cf)d_in[19];
    cf bv        = (cf)d_in[20];
    cf wv_w      = (cf)d_in[21];
    cf vis_w     = (cf)d_in[22];
    cf vis_b     = (cf)d_in[23];
    cf sem_w     = (cf)d_in[24];
    cf sem_b     = (cf)d_in[25];
    cf W_ih      = (cf)d_in[26];
    cf W_hh      = (cf)d_in[27];
    cf b_ih      = (cf)d_in[28];
    cf b_hh      = (cf)d_in[29];
    cf to_word_w = (cf)d_in[30];
    cf to_word_b = (cf)d_in[31];
    cf logit_w   = (cf)d_in[32];
    cf logit_b   = (cf)d_in[33];

    typedef __hip_bfloat16 bf;
    char* p = (char*)d_ws;
    auto take = [&](size_t bytes) { char* r = p; p += (bytes + 255) & ~(size_t)255; return r; };

    // Workspace total ~54.8 MB (baseline-proven envelope was ~56 MB).
    float* Wh   = (float*)take((size_t)B * H * 4);           // 2 MB
    bf* x       = (bf*)take((size_t)B * 2048 * 2);           // [vis|sem|embed|h0]  4 MB
    bf* xvis    = (bf*)take((size_t)B * 1536 * 2);           // 3 MB
    bf* xsem    = (bf*)take((size_t)B * S3p * 2);            // 1.81 MB
    bf* h_bf    = (bf*)take((size_t)B * H * 2);              // 1 MB
    bf* word    = (bf*)take((size_t)B * E * 2);              // 1 MB
    // region shared in time: U (attn phase) then gates (LSTM phase)
    char* region = take((size_t)B * NO * H * 2);             // 36 MB
    bf* U        = (bf*)region;
    float* gates = (float*)region;                           // 8 MB needed
    // serial weight scratch (each cvt->GEMM pair is stream-ordered)
    bf* ws = (bf*)take((size_t)2048 * 1536 * 2);             // 6 MB (max = W_ih)

    float* out_logp = (float*)d_out;
    float* out_h = out_logp + (size_t)B * V;
    float* out_c = out_h + (size_t)B * H;

    const dim3 blk(TPB);
    auto g128 = [](int M, int N) { return dim3((unsigned)(N >> 7), (unsigned)(M >> 7)); };
    auto cvt = [&](const float* src, long sld, bf* dst, long dld,
                   int rd, int cd, int rs, int cs) {
        const int total = rd * (cd >> 2);
        cvt2bf<<<(total + TPB - 1) / TPB, blk, 0, stream>>>(src, sld, dst, dld, rd, cd, rs, cs);
    };

    // ---- direct concat fills (fp32 -> bf16, with K-pad zeroing) ----
    cvt(h0, H, x + 1536, 2048, B, H, B, H);                  // h0 -> x[:,1536:2048]
    cvt(embed, E, x + 1024, 2048, B, E, B, E);               // embed -> x[:,1024:1536]
    cvt(act_sem, S, xsem + S, S3p, B, S, B, S);
    cvt(vid_sem, S, xsem + 2 * S, S3p, B, S, B, S);
    cvt(act_sem, S, xsem + 3 * S, S3p, B, S3p - 3 * S, 0, 0); // zeros cols 900..927

    // 1. Wh = h0 @ W_w^T  (fp32 out)
    cvt(W_w, H, ws, H, H, H, H, H);
    gemm_bf<bf, bf, float, false, false, false, false><<<g128(B, H), blk, 0, stream>>>(
        x + 1536, 2048, H, ws, H, 0, Wh, H, nullptr, H, H);

    // 2. objects attention -> xvis[:, 1024:1536]
    cvt(Uo_w, H, ws, H, H, H, H, H);
    gemm_bf<float, bf, bf, false, false, false, false><<<g128(B * NO, H), blk, 0, stream>>>(
        objects, H, H, ws, H, 0, U, H, nullptr, H, H);
    attn_kernel<<<B, blk, 0, stream>>>(Wh, U, objects, H, bo, wo_w, xvis + 2 * H, 1536, NO, H);

    // 3. motion attention -> xvis[:, 512:1024]
    cvt(Um_w, H, ws, H, H, H, H, H);
    gemm_bf<float, bf, bf, false, false, false, false><<<g128(B * NA, H), blk, 0, stream>>>(
        action, H, H, ws, H, 0, U, H, nullptr, H, H);
    attn_kernel<<<B, blk, 0, stream>>>(Wh, U, action, H, bm, wm_w, xvis + H, 1536, NA, H);

    // 4. video attention -> xvis[:, 0:512]
    cvt(Uv_w, H, ws, H, H, H, H, H);
    gemm_bf<float, bf, bf, false, false, false, false><<<g128(B * NV_, H), blk, 0, stream>>>(
        video, H, H, ws, H, 0, U, H, nullptr, H, H);
    attn_kernel<<<B, blk, 0, stream>>>(Wh, U, video, H, bv, wv_w, xvis, 1536, NV_, H);

    // 5. semantic attention -> xsem[:, 0:300]   (K padded 300->320)
    cvt(Uos_w, S, ws, Sp, H, Sp, H, S);
    gemm_bf<float, bf, bf, false, false, false, false><<<g128(B * NOS, H), blk, 0, stream>>>(
        obj_sem, S, S, ws, Sp, 0, U, H, nullptr, H, Sp);
    attn_kernel<<<B, blk, 0, stream>>>(Wh, U, obj_sem, S, bos, wos_w, xsem, S3p, NOS, S);

    // 6. visual = xvis @ vis_w^T + vis_b -> x[:, 0:512]
    cvt(vis_w, 3 * H, ws, 3 * H, H, 3 * H, H, 3 * H);
    gemm_bf<bf, bf, bf, false, true, false, false><<<g128(B, H), blk, 0, stream>>>(
        xvis, 1536, 1536, ws, 1536, 0, x, 2048, vis_b, H, 1536);

    // 7. sem = xsem @ sem_w^T + sem_b -> x[:, 512:1024]
    cvt(sem_w, 3 * S, ws, S3p, H, S3p, H, 3 * S);
    gemm_bf<bf, bf, bf, false, true, false, false><<<g128(B, H), blk, 0, stream>>>(
        xsem, S3p, S3p, ws, S3p, 0, x + H, 2048, sem_b, H, S3p);

    // 8. gates = x[:, :1536] @ W_ih^T ; gates += h0 @ W_hh^T  (fp32)
    cvt(W_ih, 2 * H + E, ws, 1536, 2048, 1536, 2048, 1536);
    gemm_bf<bf, bf, float, false, false, false, false><<<g128(B, 2048), blk, 0, stream>>>(
        x, 2048, 1536, ws, 1536, 0, gates, 2048, nullptr, 2048, 1536);
    cvt(W_hh, H, ws, H, 2048, H, 2048, H);
    gemm_bf<bf, bf, float, true, false, false, false><<<g128(B, 2048), blk, 0, stream>>>(
        x + 1536, 2048, H, ws, H, 0, gates, 2048, nullptr, 2048, H);

    // 9. LSTM pointwise -> out_h, out_c (fp32), h_bf (bf16)
    lstm_kernel<<<(B * H) / TPB, blk, 0, stream>>>(gates, b_ih, b_hh, c0, out_h, out_c, h_bf);

    // 10. word = h @ to_word_w^T + b
    cvt(to_word_w, H, ws, H, E, H, E, H);
    gemm_bf<bf, bf, bf, false, true, false, false><<<g128(B, E), blk, 0, stream>>>(
        h_bf, H, H, ws, H, 0, word, E, to_word_b, E, H);

    // 11. logits = word @ logit_w^T + b  (B fp32 VALU-staged, row-guarded;
    //     M-fast grid so blocks sharing a logit_w panel are dispatch-adjacent)
    gemm_bf<bf, float, float, false, true, true, true><<<dim3(B / 128, (V + 127) / 128), blk, 0, stream>>>(
        word, E, E, logit_w, E, V, out_logp, (long)V, logit_b, V, E);

    // 12. row log-softmax (online max/sum + subtract)
    logsoftmax2<<<B, blk, 0, stream>>>(out_logp, V);
}

// Round 3
// 1187.771 us; speedup vs baseline: 1.4359x; 1.0202x over previous
//
#include <hip/hip_runtime.h>
#include <hip/hip_bf16.h>
#include <cstdint>
#include <cstddef>
#include <type_traits>

#define TPB 256

typedef __attribute__((ext_vector_type(8))) short short8;
typedef __attribute__((ext_vector_type(4))) float floatx4;

__device__ __forceinline__ float bfbits2f(short v) {
    union { unsigned u; float f; } t;
    t.u = ((unsigned)(unsigned short)v) << 16;
    return t.f;
}

__device__ __forceinline__ void store_c(float* C, size_t off, float v) { C[off] = v; }
__device__ __forceinline__ void store_c(__hip_bfloat16* C, size_t off, float v) { C[off] = __float2bfloat16(v); }

// async global->LDS, 16B per lane. Dest must be wave-uniform base + lane*16.
__device__ __forceinline__ void gload16(const __hip_bfloat16* g, __hip_bfloat16* l) {
    __builtin_amdgcn_global_load_lds(
        (const __attribute__((address_space(1))) void*)g,
        (__attribute__((address_space(3))) void*)l, 16, 0, 0);
}

// VALU-staged fp32 chunk: load 8 fp32 (guarded), convert, write to swizzled slot.
// Slot c (0..511) of a 128x32 bf16 tile holds global chunk q=(c&3)^((r>>1)&3)
// of row r=c>>2 (same layout the async path produces via pre-swizzled source).
template<bool ROWG>
__device__ __forceinline__ void stage_cvt(const float* __restrict__ Msrc, long ld,
                                          long rowlim, int klim,
                                          long tilebase, int k0,
                                          __hip_bfloat16* Ls, int c)
{
    const int r = c >> 2;
    const int q = (c & 3) ^ ((r >> 1) & 3);
    const long gr = tilebase + r;
    const int gc = k0 + q * 8;
    union { __hip_bfloat16 h[8]; uint4 u4; } t;
    const bool rowok = !ROWG || (gr < rowlim);
    if (rowok && gc + 8 <= klim) {
        const float* s = Msrc + gr * ld + gc;
        const float4 v0 = *(const float4*)s;
        const float4 v1 = *(const float4*)(s + 4);
        t.h[0] = __float2bfloat16(v0.x); t.h[1] = __float2bfloat16(v0.y);
        t.h[2] = __float2bfloat16(v0.z); t.h[3] = __float2bfloat16(v0.w);
        t.h[4] = __float2bfloat16(v1.x); t.h[5] = __float2bfloat16(v1.y);
        t.h[6] = __float2bfloat16(v1.z); t.h[7] = __float2bfloat16(v1.w);
    } else {
#pragma unroll
        for (int e = 0; e < 8; ++e) {
            const float v = (rowok && (gc + e) < klim) ? Msrc[gr * ld + gc + e] : 0.f;
            t.h[e] = __float2bfloat16(v);
        }
    }
    *(uint4*)(&Ls[c * 8]) = t.u4;
}

// ---------------------------------------------------------------------------
// GEMM: C[M,N] = A[M,K] @ B[N,K]^T (+ bias[n]) (+= C if ACC).
// bf16 operand: async global_load_lds; fp32 operand: VALU-staged (guarded).
// LDS XOR-chunk-swizzled both sides.  XCD-aware bijective block swizzle:
// linear id -> contiguous work chunk per XCD, x-dim fastest within chunk, so
// blocks sharing a 128-row operand panel live on one XCD's L2.
// FUSE: epilogue accumulates per-row sum(exp(v)) into rowsum[] (log-softmax
// pass-1 fusion; valid cols only; rows must be exact).
// ---------------------------------------------------------------------------
template<typename TA, typename TB, typename OutT, bool ACC, bool BIAS, bool NEDGE, bool SWAPGRID, bool FUSE>
__global__ __launch_bounds__(TPB)
void gemm_bf(const TA* __restrict__ A, int lda, int Ka,
             const TB* __restrict__ Bm, int ldb, long NBrow,
             OutT* __restrict__ C, long ldc,
             const float* __restrict__ bias,
             int N, int K,
             float* __restrict__ rowsum)
{
    constexpr bool AF32 = std::is_same<TA, float>::value;
    constexpr bool BF32 = std::is_same<TB, float>::value;

    __shared__ __align__(16) __hip_bfloat16 As[128 * 32];
    __shared__ __align__(16) __hip_bfloat16 Bs[128 * 32];
    __shared__ float smrow[128];

    const int tid  = threadIdx.x;
    const int lane = tid & 63;
    const int wave = tid >> 6;
    const int wm   = (wave & 1) * 64;
    const int wn   = (wave >> 1) * 64;
    const int l15  = lane & 15;
    const int quad = lane >> 4;

    // XCD bijective remap: hw dispatch linearizes x-fast; xcd = id % 8.
    const unsigned gx = gridDim.x;
    const unsigned l  = blockIdx.y * gx + blockIdx.x;
    const unsigned nwg = gx * gridDim.y;
    const unsigned q8 = nwg >> 3, r8 = nwg & 7;
    const unsigned c8 = l & 7, i8 = l >> 3;
    const unsigned w  = (c8 < r8 ? c8 * (q8 + 1) : r8 * (q8 + 1) + (c8 - r8) * q8) + i8;
    const unsigned bx = w % gx, by = w / gx;
    const long tileM = (long)(SWAPGRID ? bx : by) * 128;
    const long tileN = (long)(SWAPGRID ? by : bx) * 128;

    const int c0 = tid, c1 = tid + 256;
    const int r0 = c0 >> 2, r1 = c1 >> 2;
    const int q0 = (c0 & 3) ^ ((r0 >> 1) & 3);
    const int q1 = (c1 & 3) ^ ((r1 >> 1) & 3);

    const __hip_bfloat16* a0 = nullptr; const __hip_bfloat16* a1 = nullptr;
    const __hip_bfloat16* b0 = nullptr; const __hip_bfloat16* b1 = nullptr;
    if constexpr (!AF32) {
        a0 = (const __hip_bfloat16*)A + (tileM + r0) * (long)lda + q0 * 8;
        a1 = (const __hip_bfloat16*)A + (tileM + r1) * (long)lda + q1 * 8;
    }
    if constexpr (!BF32) {
        b0 = (const __hip_bfloat16*)Bm + (tileN + r0) * (long)ldb + q0 * 8;
        b1 = (const __hip_bfloat16*)Bm + (tileN + r1) * (long)ldb + q1 * 8;
    }
    __hip_bfloat16* la0 = &As[c0 * 8];
    __hip_bfloat16* la1 = &As[c1 * 8];
    __hip_bfloat16* lb0 = &Bs[c0 * 8];
    __hip_bfloat16* lb1 = &Bs[c1 * 8];

    const int qs = quad ^ ((l15 >> 1) & 3);   // swizzled read chunk

    floatx4 acc[4][4];
#pragma unroll
    for (int i = 0; i < 4; ++i)
#pragma unroll
        for (int j = 0; j < 4; ++j)
            acc[i][j] = (floatx4){0.f, 0.f, 0.f, 0.f};

    for (int k0 = 0; k0 < K; k0 += 32) {
        if constexpr (!AF32) { gload16(a0, la0); gload16(a1, la1); a0 += 32; a1 += 32; }
        if constexpr (!BF32) { gload16(b0, lb0); gload16(b1, lb1); b0 += 32; b1 += 32; }
        if constexpr (AF32) {
            stage_cvt<false>((const float*)A, lda, 0, Ka, tileM, k0, As, c0);
            stage_cvt<false>((const float*)A, lda, 0, Ka, tileM, k0, As, c1);
        }
        if constexpr (BF32) {
            stage_cvt<true>((const float*)Bm, ldb, NBrow, K, tileN, k0, Bs, c0);
            stage_cvt<true>((const float*)Bm, ldb, NBrow, K, tileN, k0, Bs, c1);
        }
        __syncthreads();   // drains vmcnt+lgkmcnt before barrier

        short8 af[4], bfg[4];
#pragma unroll
        for (int i = 0; i < 4; ++i)
            af[i] = *(const short8*)(&As[(wm + i * 16 + l15) * 32 + qs * 8]);
#pragma unroll
        for (int j = 0; j < 4; ++j)
            bfg[j] = *(const short8*)(&Bs[(wn + j * 16 + l15) * 32 + qs * 8]);
#pragma unroll
        for (int i = 0; i < 4; ++i)
#pragma unroll
            for (int j = 0; j < 4; ++j)
                acc[i][j] = __builtin_amdgcn_mfma_f32_16x16x32_bf16(af[i], bfg[j], acc[i][j], 0, 0, 0);
        __syncthreads();
    }

    if constexpr (FUSE) {
        for (int t = tid; t < 128; t += TPB) smrow[t] = 0.f;
        __syncthreads();
    }
#pragma unroll
    for (int i = 0; i < 4; ++i) {
        float es[4] = {0.f, 0.f, 0.f, 0.f};
#pragma unroll
        for (int j = 0; j < 4; ++j) {
            const long n = tileN + wn + j * 16 + l15;
            if (NEDGE && n >= N) continue;
            float bv = 0.f;
            if constexpr (BIAS) bv = bias[n];
#pragma unroll
            for (int r = 0; r < 4; ++r) {
                const long m = tileM + wm + i * 16 + quad * 4 + r;
                const size_t off = (size_t)(m * ldc + n);
                float v = acc[i][j][r] + bv;
                if constexpr (ACC) v += ((const float*)C)[off];
                store_c(C, off, v);
                if constexpr (FUSE) es[r] += __expf(v);
            }
        }
        if constexpr (FUSE) {
#pragma unroll
            for (int r = 0; r < 4; ++r)
                atomicAdd(&smrow[wm + i * 16 + quad * 4 + r], es[r]);
        }
    }
    if constexpr (FUSE) {
        __syncthreads();
        for (int t = tid; t < 128; t += TPB)
            atomicAdd(&rowsum[tileM + t], smrow[t]);
    }
}

// ---------------------------------------------------------------------------
// fp32 -> bf16 strided convert with zero padding outside [rows_src, cols_src)
// ---------------------------------------------------------------------------
union Bf4 { __hip_bfloat16 h[4]; uint2 u; };

__global__ __launch_bounds__(TPB)
void cvt2bf(const float* __restrict__ src, long sld,
            __hip_bfloat16* __restrict__ dst, long dld,
            int rows_dst, int cols_dst, int rows_src, int cols_src)
{
    const int idx = blockIdx.x * TPB + threadIdx.x;     // one per 4 dst cols
    const int cpr = cols_dst >> 2;
    if (idx >= rows_dst * cpr) return;
    const int r  = idx / cpr;
    const int c4 = (idx - r * cpr) << 2;
    Bf4 o;
    if (r < rows_src && c4 + 4 <= cols_src) {
        const float4 v = *(const float4*)(src + (long)r * sld + c4);
        o.h[0] = __float2bfloat16(v.x); o.h[1] = __float2bfloat16(v.y);
        o.h[2] = __float2bfloat16(v.z); o.h[3] = __float2bfloat16(v.w);
    } else {
#pragma unroll
        for (int e = 0; e < 4; ++e) {
            const float v = (r < rows_src && (c4 + e) < cols_src)
                              ? src[(long)r * sld + c4 + e] : 0.f;
            o.h[e] = __float2bfloat16(v);
        }
    }
    *(uint2*)(dst + (long)r * dld + c4) = o.u;
}

// ---------------------------------------------------------------------------
// Bahdanau attention, one batch row per block. U bf16, feats fp32.
// ---------------------------------------------------------------------------
__global__ __launch_bounds__(TPB)
void attn_kernel(const float* __restrict__ Wh,
                 const __hip_bfloat16* __restrict__ U,
                 const float* __restrict__ feats, int feats_ld,
                 const float* __restrict__ bias,
                 const float* __restrict__ w,
                 __hip_bfloat16* __restrict__ dst,
                 int dst_ld, int N, int D)
{
    const int b = blockIdx.x;
    const int tid = threadIdx.x;
    const int lane = tid & 63;
    const int wave = tid >> 6;
    __shared__ float sc[64];

    const float* whb = Wh + (size_t)b * 512;
    const int hoff = lane * 8;             // 64 lanes x 8 = 512 exactly
    float wh[8], bb[8], ww[8];
    {
        float4 t0 = *(const float4*)(whb + hoff), t1 = *(const float4*)(whb + hoff + 4);
        wh[0]=t0.x; wh[1]=t0.y; wh[2]=t0.z; wh[3]=t0.w; wh[4]=t1.x; wh[5]=t1.y; wh[6]=t1.z; wh[7]=t1.w;
        t0 = *(const float4*)(bias + hoff); t1 = *(const float4*)(bias + hoff + 4);
        bb[0]=t0.x; bb[1]=t0.y; bb[2]=t0.z; bb[3]=t0.w; bb[4]=t1.x; bb[5]=t1.y; bb[6]=t1.z; bb[7]=t1.w;
        t0 = *(const float4*)(w + hoff); t1 = *(const float4*)(w + hoff + 4);
        ww[0]=t0.x; ww[1]=t0.y; ww[2]=t0.z; ww[3]=t0.w; ww[4]=t1.x; ww[5]=t1.y; ww[6]=t1.z; ww[7]=t1.w;
    }
    for (int n = wave; n < N; n += 4) {
        const short8 u = *(const short8*)(U + ((size_t)b * N + n) * 512 + hoff);
        float s = 0.f;
#pragma unroll
        for (int e = 0; e < 8; ++e)
            s += tanhf(wh[e] + bfbits2f(u[e]) + bb[e]) * ww[e];
#pragma unroll
        for (int off = 32; off > 0; off >>= 1) s += __shfl_down(s, off);
        if (lane == 0) sc[n] = s;
    }
    __syncthreads();
    if (tid == 0) {
        float mx = -3.4e38f;
        for (int n = 0; n < N; ++n) mx = fmaxf(mx, sc[n]);
        float sum = 0.f;
        for (int n = 0; n < N; ++n) { float e = expf(sc[n] - mx); sc[n] = e; sum += e; }
        const float inv = 1.f / sum;
        for (int n = 0; n < N; ++n) sc[n] *= inv;
    }
    __syncthreads();
    for (int d = tid; d < D; d += TPB) {
        float a = 0.f;
        for (int n = 0; n < N; ++n)
            a += sc[n] * feats[((size_t)b * N + n) * feats_ld + d];
        dst[(size_t)b * dst_ld + d] = __float2bfloat16(a);
    }
}

__device__ __forceinline__ float sigmoidf_(float x) { return 1.f / (1.f + expf(-x)); }

__global__ __launch_bounds__(TPB)
void lstm_kernel(const float* __restrict__ gates,
                 const float* __restrict__ b_ih,
                 const float* __restrict__ b_hh,
                 const float* __restrict__ c0,
                 float* __restrict__ out_h,
                 float* __restrict__ out_c,
                 __hip_bfloat16* __restrict__ h_bf,
                 float* __restrict__ rowsum)
{
    const int idx = blockIdx.x * TPB + threadIdx.x;   // B*H threads
    if (idx >= 1024 * 512) return;
    if (idx < 1024) rowsum[idx] = 0.f;                // zero log-softmax sums
    const int hh = idx & 511;
    const float* g = gates + (size_t)(idx >> 9) * 2048;
    const float gi = g[hh]        + b_ih[hh]        + b_hh[hh];
    const float gf = g[512 + hh]  + b_ih[512 + hh]  + b_hh[512 + hh];
    const float gg = g[1024 + hh] + b_ih[1024 + hh] + b_hh[1024 + hh];
    const float go = g[1536 + hh] + b_ih[1536 + hh] + b_hh[1536 + hh];
    const float c = sigmoidf_(gf) * c0[idx] + sigmoidf_(gi) * tanhf(gg);
    const float h = sigmoidf_(go) * tanhf(c);
    out_h[idx] = h;
    out_c[idx] = c;
    h_bf[idx]  = __float2bfloat16(h);
}

// ---------------------------------------------------------------------------
// final log-softmax pass: row -= log(rowsum[b])  (sum accumulated in GEMM)
// ---------------------------------------------------------------------------
__global__ __launch_bounds__(TPB)
void lsub(float* __restrict__ logits, const float* __restrict__ rowsum, int V)
{
    const int b = blockIdx.y;
    float* row = logits + (size_t)b * V;
    const float lse = logf(rowsum[b]);
    const int tid = threadIdx.x;
    const int mis  = (int)(((uintptr_t)row >> 2) & 3);
    const int head = mis ? 4 - mis : 0;
    const int nv   = (V - head) >> 2;
    const int tail0 = head + nv * 4;
    if (blockIdx.x == 0) {
        if (tid < head) row[tid] -= lse;
        for (int i = tail0 + tid; i < V; i += TPB) row[i] -= lse;
    }
    for (int k = blockIdx.x * TPB + tid; k < nv; k += gridDim.x * TPB) {
        float4 x = *(const float4*)(row + head + 4 * k);
        x.x -= lse; x.y -= lse; x.z -= lse; x.w -= lse;
        *(float4*)(row + head + 4 * k) = x;
    }
}

// ---------------------------------------------------------------------------

extern "C" void kernel_launch(void* const* d_in, const int* in_sizes, int n_in,
                              void* d_out, int out_size, void* d_ws, size_t ws_size,
                              hipStream_t stream)
{
    (void)in_sizes; (void)n_in; (void)out_size; (void)ws_size;
    const int B = 1024, H = 512, S = 300, E = 512, V = 50257;
    const int NO = 36, NA = 26, NV_ = 26, NOS = 20;
    const int Sp = 320;      // S padded to multiple of 32 (K of semantic U GEMM)
    const int S3p = 928;     // 3*S=900 padded to multiple of 32

    typedef const float* cf;
    cf objects   = (cf)d_in[0];
    cf action    = (cf)d_in[1];
    cf video     = (cf)d_in[2];
    cf obj_sem   = (cf)d_in[3];
    cf act_sem   = (cf)d_in[4];
    cf vid_sem   = (cf)d_in[5];
    cf embed     = (cf)d_in[6];
    cf h0        = (cf)d_in[7];
    cf c0        = (cf)d_in[8];
    cf W_w       = (cf)d_in[9];
    cf Uo_w      = (cf)d_in[10];
    cf bo        = (cf)d_in[11];
    cf wo_w      = (cf)d_in[12];
    cf Uos_w     = (cf)d_in[13];
    cf bos       = (cf)d_in[14];
    cf wos_w     = (cf)d_in[15];
    cf Um_w      = (cf)d_in[16];
    cf bm        = (cf)d_in[17];
    cf wm_w      = (cf)d_in[18];
    cf Uv_w      = (cf)d_in[19];
    cf bv        = (cf)d_in[20];
    cf wv_w      = (cf)d_in[21];
    cf vis_w     = (cf)d_in[22];
    cf vis_b     = (cf)d_in[23];
    cf sem_w     = (cf)d_in[24];
    cf sem_b     = (cf)d_in[25];
    cf W_ih      = (cf)d_in[26];
    cf W_hh      = (cf)d_in[27];
    cf b_ih      = (cf)d_in[28];
    cf b_hh      = (cf)d_in[29];
    cf to_word_w = (cf)d_in[30];
    cf to_word_b = (cf)d_in[31];
    cf logit_w   = (cf)d_in[32];
    cf logit_b   = (cf)d_in[33];

    typedef __hip_bfloat16 bf;
    char* p = (char*)d_ws;
    auto take = [&](size_t bytes) { char* r = p; p += (bytes + 255) & ~(size_t)255; return r; };

    // Workspace total ~50.3 MiB (proven envelope ~55.8 MiB).
    float* Wh   = (float*)take((size_t)B * H * 4);           // 2 MiB
    bf* x       = (bf*)take((size_t)B * 2048 * 2);           // [vis|sem|embed|h0]  4 MiB
    bf* xvis    = (bf*)take((size_t)B * 1536 * 2);           // 3 MiB
    bf* xsem    = (bf*)take((size_t)B * S3p * 2);            // 1.81 MiB
    bf* h_bf    = (bf*)take((size_t)B * H * 2);              // 1 MiB
    bf* word    = (bf*)take((size_t)B * E * 2);              // 1 MiB
    // region 36 MiB, time-shared:
    //   [0..36)  U during attn phase
    //   [0..8)   gates (fp32) during LSTM phase
    //   [28..36) Wcat = [W_ih|W_hh] bf16 (converted after last attn)
    char* region = take((size_t)B * NO * H * 2);
    bf* U        = (bf*)region;
    float* gates = (float*)region;
    bf* Wcat     = (bf*)(region + (size_t)28 * 1024 * 1024);
    bf* wsm = (bf*)take((size_t)512 * 1536 * 2);             // 1.5 MiB weight scratch
    float* rowsum = (float*)take((size_t)B * 4);             // 4 KiB

    float* out_logp = (float*)d_out;
    float* out_h = out_logp + (size_t)B * V;
    float* out_c = out_h + (size_t)B * H;

    const dim3 blk(TPB);
    auto g128 = [](int M, int N) { return dim3((unsigned)(N >> 7), (unsigned)(M >> 7)); };
    auto cvt = [&](const float* src, long sld, bf* dst, long dld,
                   int rd, int cd, int rs, int cs) {
        const int total = rd * (cd >> 2);
        cvt2bf<<<(total + TPB - 1) / TPB, blk, 0, stream>>>(src, sld, dst, dld, rd, cd, rs, cs);
    };

    // ---- direct concat fills (fp32 -> bf16, with K-pad zeroing) ----
    cvt(h0, H, x + 1536, 2048, B, H, B, H);                  // h0 -> x[:,1536:2048]
    cvt(embed, E, x + 1024, 2048, B, E, B, E);               // embed -> x[:,1024:1536]
    cvt(act_sem, S, xsem + S, S3p, B, S, B, S);
    cvt(vid_sem, S, xsem + 2 * S, S3p, B, S, B, S);
    cvt(act_sem, S, xsem + 3 * S, S3p, B, S3p - 3 * S, 0, 0); // zeros cols 900..927

    // 1. Wh = h0 @ W_w^T  (fp32 out)
    cvt(W_w, H, wsm, H, H, H, H, H);
    gemm_bf<bf, bf, float, false, false, false, false, false><<<g128(B, H), blk, 0, stream>>>(
        x + 1536, 2048, H, wsm, H, 0, Wh, H, nullptr, H, H, nullptr);

    // 2. objects attention -> xvis[:, 1024:1536]
    cvt(Uo_w, H, wsm, H, H, H, H, H);
    gemm_bf<float, bf, bf, false, false, false, false, false><<<g128(B * NO, H), blk, 0, stream>>>(
        objects, H, H, wsm, H, 0, U, H, nullptr, H, H, nullptr);
    attn_kernel<<<B, blk, 0, stream>>>(Wh, U, objects, H, bo, wo_w, xvis + 2 * H, 1536, NO, H);

    // 3. motion attention -> xvis[:, 512:1024]
    cvt(Um_w, H, wsm, H, H, H, H, H);
    gemm_bf<float, bf, bf, false, false, false, false, false><<<g128(B * NA, H), blk, 0, stream>>>(
        action, H, H, wsm, H, 0, U, H, nullptr, H, H, nullptr);
    attn_kernel<<<B, blk, 0, stream>>>(Wh, U, action, H, bm, wm_w, xvis + H, 1536, NA, H);

    // 4. video attention -> xvis[:, 0:512]
    cvt(Uv_w, H, wsm, H, H, H, H, H);
    gemm_bf<float, bf, bf, false, false, false, false, false><<<g128(B * NV_, H), blk, 0, stream>>>(
        video, H, H, wsm, H, 0, U, H, nullptr, H, H, nullptr);
    attn_kernel<<<B, blk, 0, stream>>>(Wh, U, video, H, bv, wv_w, xvis, 1536, NV_, H);

    // 5. semantic attention -> xsem[:, 0:300]   (K padded 300->320)
    cvt(Uos_w, S, wsm, Sp, H, Sp, H, S);
    gemm_bf<float, bf, bf, false, false, false, false, false><<<g128(B * NOS, H), blk, 0, stream>>>(
        obj_sem, S, S, wsm, Sp, 0, U, H, nullptr, H, Sp, nullptr);
    attn_kernel<<<B, blk, 0, stream>>>(Wh, U, obj_sem, S, bos, wos_w, xsem, S3p, NOS, S);

    // Wcat = [W_ih | W_hh] bf16 (U dead from here; region tail reusable)
    cvt(W_ih, 2 * H + E, Wcat, 2048, 2048, 1536, 2048, 1536);
    cvt(W_hh, H, Wcat + 1536, 2048, 2048, 512, 2048, 512);

    // 6. visual = xvis @ vis_w^T + vis_b -> x[:, 0:512]
    cvt(vis_w, 3 * H, wsm, 3 * H, H, 3 * H, H, 3 * H);
    gemm_bf<bf, bf, bf, false, true, false, false, false><<<g128(B, H), blk, 0, stream>>>(
        xvis, 1536, 1536, wsm, 1536, 0, x, 2048, vis_b, H, 1536, nullptr);

    // 7. sem = xsem @ sem_w^T + sem_b -> x[:, 512:1024]
    cvt(sem_w, 3 * S, wsm, S3p, H, S3p, H, 3 * S);
    gemm_bf<bf, bf, bf, false, true, false, false, false><<<g128(B, H), blk, 0, stream>>>(
        xsem, S3p, S3p, wsm, S3p, 0, x + H, 2048, sem_b, H, S3p, nullptr);

    // 8. gates = [x|h0] @ [W_ih|W_hh]^T  (single K=2048 GEMM)
    gemm_bf<bf, bf, float, false, false, false, false, false><<<g128(B, 2048), blk, 0, stream>>>(
        x, 2048, 2048, Wcat, 2048, 0, gates, 2048, nullptr, 2048, 2048, nullptr);

    // 9. LSTM pointwise -> out_h, out_c (fp32), h_bf (bf16); zeroes rowsum
    lstm_kernel<<<(B * H) / TPB, blk, 0, stream>>>(gates, b_ih, b_hh, c0, out_h, out_c, h_bf, rowsum);

    // 10. word = h @ to_word_w^T + b
    cvt(to_word_w, H, wsm, H, E, H, E, H);
    gemm_bf<bf, bf, bf, false, true, false, false, false><<<g128(B, E), blk, 0, stream>>>(
        h_bf, H, H, wsm, H, 0, word, E, to_word_b, E, H, nullptr);

    // 11. logits = word @ logit_w^T + b; epilogue accumulates sum(exp) per row.
    //     SWAPGRID: 8 M-tiles x-fast share each logit_w panel on one XCD.
    gemm_bf<bf, float, float, false, true, true, true, true><<<dim3(B / 128, (V + 127) / 128), blk, 0, stream>>>(
        word, E, E, logit_w, E, V, out_logp, (long)V, logit_b, V, E, rowsum);

    // 12. row log-softmax subtract: row -= log(rowsum)
    lsub<<<dim3(4, B), blk, 0, stream>>>(out_logp, rowsum, V);
}

// Round 4
// 1141.427 us; speedup vs baseline: 1.4942x; 1.0406x over previous
//
#include <hip/hip_runtime.h>
#include <hip/hip_bf16.h>
#include <cstdint>
#include <cstddef>
#include <type_traits>

#define TPB 256

typedef __attribute__((ext_vector_type(8))) short short8;
typedef __attribute__((ext_vector_type(4))) float floatx4;

__device__ __forceinline__ float bfbits2f(short v) {
    union { unsigned u; float f; } t;
    t.u = ((unsigned)(unsigned short)v) << 16;
    return t.f;
}

__device__ __forceinline__ void store_c(float* C, size_t off, float v) { C[off] = v; }
__device__ __forceinline__ void store_c(__hip_bfloat16* C, size_t off, float v) { C[off] = __float2bfloat16(v); }

// async global->LDS, 16B per lane. Dest must be wave-uniform base + lane*16.
__device__ __forceinline__ void gload16(const __hip_bfloat16* g, __hip_bfloat16* l) {
    __builtin_amdgcn_global_load_lds(
        (const __attribute__((address_space(1))) void*)g,
        (__attribute__((address_space(3))) void*)l, 16, 0, 0);
}

// Guarded load of one 8-fp32 chunk for LDS slot c (swizzled chunk select).
template<bool ROWG>
__device__ __forceinline__ void load_chunk_f32(const float* __restrict__ M, long ld,
                                               long rowlim, int klim,
                                               long tilebase, int k0, int c,
                                               float4& lo, float4& hi)
{
    const int r = c >> 2;
    const int q = (c & 3) ^ ((r >> 1) & 3);
    const long gr = tilebase + r;
    const int gc = k0 + q * 8;
    const bool rowok = !ROWG || (gr < rowlim);
    if (rowok && gc + 8 <= klim) {
        const float* s = M + gr * ld + gc;
        lo = *(const float4*)s;
        hi = *(const float4*)(s + 4);
    } else {
        float v[8];
#pragma unroll
        for (int e = 0; e < 8; ++e)
            v[e] = (rowok && (gc + e) < klim) ? M[gr * ld + gc + e] : 0.f;
        lo = (float4){v[0], v[1], v[2], v[3]};
        hi = (float4){v[4], v[5], v[6], v[7]};
    }
}

__device__ __forceinline__ void cvt_write8(__hip_bfloat16* Lbase, int c, float4 lo, float4 hi)
{
    union { __hip_bfloat16 h[8]; uint4 u4; } t;
    t.h[0] = __float2bfloat16(lo.x); t.h[1] = __float2bfloat16(lo.y);
    t.h[2] = __float2bfloat16(lo.z); t.h[3] = __float2bfloat16(lo.w);
    t.h[4] = __float2bfloat16(hi.x); t.h[5] = __float2bfloat16(hi.y);
    t.h[6] = __float2bfloat16(hi.z); t.h[7] = __float2bfloat16(hi.w);
    *(uint4*)(&Lbase[c * 8]) = t.u4;
}

// ---------------------------------------------------------------------------
// GEMM: C[M,N] = A[M,K] @ B[N,K]^T (+ bias[n]) (+= C if ACC).
// bf16 operand: async global_load_lds (rows must be in-bounds / padded).
// fp32 operand: reg-staged (issue early) + cvt+ds_write after MFMA (T14).
// Double-buffered LDS, ONE barrier per K-step: prefetch t+1 overlaps MFMA t.
// LDS XOR-chunk-swizzled both sides.  XCD-aware bijective block swizzle.
// FUSE: per-row sum(exp(v)) -> rowpart[tileN_idx * M + m] (no atomics).
// ---------------------------------------------------------------------------
template<typename TA, typename TB, typename OutT, bool ACC, bool BIAS, bool NEDGE, bool SWAPGRID, bool FUSE>
__global__ __launch_bounds__(TPB)
void gemm_bf(const TA* __restrict__ A, int lda, int Ka,
             const TB* __restrict__ Bm, int ldb, long NBrow,
             OutT* __restrict__ C, long ldc,
             const float* __restrict__ bias,
             int N, int K,
             float* __restrict__ rowpart)
{
    constexpr bool AF32 = std::is_same<TA, float>::value;
    constexpr bool BF32 = std::is_same<TB, float>::value;

    __shared__ __align__(16) __hip_bfloat16 As[2][128 * 32];
    __shared__ __align__(16) __hip_bfloat16 Bs[2][128 * 32];
    __shared__ float smrow[2][128];

    const int tid  = threadIdx.x;
    const int lane = tid & 63;
    const int wave = tid >> 6;
    const int wm   = (wave & 1) * 64;
    const int wn   = (wave >> 1) * 64;
    const int l15  = lane & 15;
    const int quad = lane >> 4;

    // XCD bijective remap: hw dispatch linearizes x-fast; xcd = id % 8.
    const unsigned gx = gridDim.x;
    const unsigned l  = blockIdx.y * gx + blockIdx.x;
    const unsigned nwg = gx * gridDim.y;
    const unsigned q8 = nwg >> 3, r8 = nwg & 7;
    const unsigned c8 = l & 7, i8 = l >> 3;
    const unsigned w  = (c8 < r8 ? c8 * (q8 + 1) : r8 * (q8 + 1) + (c8 - r8) * q8) + i8;
    const unsigned bx = w % gx, by = w / gx;
    const long tileM = (long)(SWAPGRID ? bx : by) * 128;
    const long tileN = (long)(SWAPGRID ? by : bx) * 128;

    const int c0 = tid, c1 = tid + 256;
    const int r0 = c0 >> 2, r1 = c1 >> 2;
    const int q0 = (c0 & 3) ^ ((r0 >> 1) & 3);
    const int q1 = (c1 & 3) ^ ((r1 >> 1) & 3);

    // bf16 async source pointers at k=0 (advance by +k elements)
    const __hip_bfloat16* a0 = nullptr; const __hip_bfloat16* a1 = nullptr;
    const __hip_bfloat16* b0 = nullptr; const __hip_bfloat16* b1 = nullptr;
    if constexpr (!AF32) {
        a0 = (const __hip_bfloat16*)A + (tileM + r0) * (long)lda + q0 * 8;
        a1 = (const __hip_bfloat16*)A + (tileM + r1) * (long)lda + q1 * 8;
    }
    if constexpr (!BF32) {
        b0 = (const __hip_bfloat16*)Bm + (tileN + r0) * (long)ldb + q0 * 8;
        b1 = (const __hip_bfloat16*)Bm + (tileN + r1) * (long)ldb + q1 * 8;
    }
    const float* Af = (const float*)A;
    const float* Bf = (const float*)Bm;

    const int qs = quad ^ ((l15 >> 1) & 3);   // swizzled read chunk

    floatx4 acc[4][4];
#pragma unroll
    for (int i = 0; i < 4; ++i)
#pragma unroll
        for (int j = 0; j < 4; ++j)
            acc[i][j] = (floatx4){0.f, 0.f, 0.f, 0.f};

    auto compute = [&](int cb) {
        short8 af[4], bfg[4];
#pragma unroll
        for (int i = 0; i < 4; ++i)
            af[i] = *(const short8*)(&As[cb][(wm + i * 16 + l15) * 32 + qs * 8]);
#pragma unroll
        for (int j = 0; j < 4; ++j)
            bfg[j] = *(const short8*)(&Bs[cb][(wn + j * 16 + l15) * 32 + qs * 8]);
#pragma unroll
        for (int i = 0; i < 4; ++i)
#pragma unroll
            for (int j = 0; j < 4; ++j)
                acc[i][j] = __builtin_amdgcn_mfma_f32_16x16x32_bf16(af[i], bfg[j], acc[i][j], 0, 0, 0);
    };

    const int nt = K >> 5;

    // prologue: stage tile 0 into buffer 0
    if constexpr (!AF32) { gload16(a0, &As[0][c0 * 8]); gload16(a1, &As[0][c1 * 8]); }
    else {
        float4 lo0, hi0, lo1, hi1;
        load_chunk_f32<false>(Af, lda, 0, Ka, tileM, 0, c0, lo0, hi0);
        load_chunk_f32<false>(Af, lda, 0, Ka, tileM, 0, c1, lo1, hi1);
        cvt_write8(As[0], c0, lo0, hi0);
        cvt_write8(As[0], c1, lo1, hi1);
    }
    if constexpr (!BF32) { gload16(b0, &Bs[0][c0 * 8]); gload16(b1, &Bs[0][c1 * 8]); }
    else {
        float4 lo0, hi0, lo1, hi1;
        load_chunk_f32<true>(Bf, ldb, NBrow, K, tileN, 0, c0, lo0, hi0);
        load_chunk_f32<true>(Bf, ldb, NBrow, K, tileN, 0, c1, lo1, hi1);
        cvt_write8(Bs[0], c0, lo0, hi0);
        cvt_write8(Bs[0], c1, lo1, hi1);
    }
    __syncthreads();

    int cur = 0;
    for (int t = 0; t + 1 < nt; ++t) {
        const int kn = (t + 1) << 5;
        float4 xl0, xh0, xl1, xh1;   // A prefetch regs (AF32)
        float4 yl0, yh0, yl1, yh1;   // B prefetch regs (BF32)
        // issue next-tile loads first: latency hides under MFMA below
        if constexpr (!AF32) { gload16(a0 + kn, &As[cur ^ 1][c0 * 8]); gload16(a1 + kn, &As[cur ^ 1][c1 * 8]); }
        else {
            load_chunk_f32<false>(Af, lda, 0, Ka, tileM, kn, c0, xl0, xh0);
            load_chunk_f32<false>(Af, lda, 0, Ka, tileM, kn, c1, xl1, xh1);
        }
        if constexpr (!BF32) { gload16(b0 + kn, &Bs[cur ^ 1][c0 * 8]); gload16(b1 + kn, &Bs[cur ^ 1][c1 * 8]); }
        else {
            load_chunk_f32<true>(Bf, ldb, NBrow, K, tileN, kn, c0, yl0, yh0);
            load_chunk_f32<true>(Bf, ldb, NBrow, K, tileN, kn, c1, yl1, yh1);
        }

        compute(cur);

        // write staged regs AFTER MFMA so MFMA's lgkm wait excludes them
        if constexpr (AF32) { cvt_write8(As[cur ^ 1], c0, xl0, xh0); cvt_write8(As[cur ^ 1], c1, xl1, xh1); }
        if constexpr (BF32) { cvt_write8(Bs[cur ^ 1], c0, yl0, yh0); cvt_write8(Bs[cur ^ 1], c1, yl1, yh1); }
        __syncthreads();
        cur ^= 1;
    }
    compute(cur);

#pragma unroll
    for (int i = 0; i < 4; ++i) {
        float es[4] = {0.f, 0.f, 0.f, 0.f};
#pragma unroll
        for (int j = 0; j < 4; ++j) {
            const long n = tileN + wn + j * 16 + l15;
            if (NEDGE && n >= N) continue;
            float bv = 0.f;
            if constexpr (BIAS) bv = bias[n];
#pragma unroll
            for (int r = 0; r < 4; ++r) {
                const long m = tileM + wm + i * 16 + quad * 4 + r;
                const size_t off = (size_t)(m * ldc + n);
                float v = acc[i][j][r] + bv;
                if constexpr (ACC) v += ((const float*)C)[off];
                store_c(C, off, v);
                if constexpr (FUSE) es[r] += __expf(v);
            }
        }
        if constexpr (FUSE) {
#pragma unroll
            for (int r = 0; r < 4; ++r) {
                float v = es[r];
                v += __shfl_xor(v, 1);
                v += __shfl_xor(v, 2);
                v += __shfl_xor(v, 4);
                v += __shfl_xor(v, 8);
                if (l15 == 0) smrow[wave >> 1][wm + i * 16 + quad * 4 + r] = v;
            }
        }
    }
    if constexpr (FUSE) {
        __syncthreads();
        if (tid < 128) {
            const long Mtot = (long)(SWAPGRID ? gridDim.x : gridDim.y) * 128;
            rowpart[(size_t)(tileN >> 7) * Mtot + tileM + tid] = smrow[0][tid] + smrow[1][tid];
        }
    }
}

// ---------------------------------------------------------------------------
// fp32 -> bf16 strided convert with zero padding outside [rows_src, cols_src)
// ---------------------------------------------------------------------------
union Bf4 { __hip_bfloat16 h[4]; uint2 u; };

__global__ __launch_bounds__(TPB)
void cvt2bf(const float* __restrict__ src, long sld,
            __hip_bfloat16* __restrict__ dst, long dld,
            int rows_dst, int cols_dst, int rows_src, int cols_src)
{
    const int idx = blockIdx.x * TPB + threadIdx.x;     // one per 4 dst cols
    const int cpr = cols_dst >> 2;
    if (idx >= rows_dst * cpr) return;
    const int r  = idx / cpr;
    const int c4 = (idx - r * cpr) << 2;
    Bf4 o;
    if (r < rows_src && c4 + 4 <= cols_src) {
        const float4 v = *(const float4*)(src + (long)r * sld + c4);
        o.h[0] = __float2bfloat16(v.x); o.h[1] = __float2bfloat16(v.y);
        o.h[2] = __float2bfloat16(v.z); o.h[3] = __float2bfloat16(v.w);
    } else {
#pragma unroll
        for (int e = 0; e < 4; ++e) {
            const float v = (r < rows_src && (c4 + e) < cols_src)
                              ? src[(long)r * sld + c4 + e] : 0.f;
            o.h[e] = __float2bfloat16(v);
        }
    }
    *(uint2*)(dst + (long)r * dld + c4) = o.u;
}

// ---------------------------------------------------------------------------
// Bahdanau attention, one batch row per block. U bf16, feats fp32.
// ---------------------------------------------------------------------------
__global__ __launch_bounds__(TPB)
void attn_kernel(const float* __restrict__ Wh,
                 const __hip_bfloat16* __restrict__ U,
                 const float* __restrict__ feats, int feats_ld,
                 const float* __restrict__ bias,
                 const float* __restrict__ w,
                 __hip_bfloat16* __restrict__ dst,
                 int dst_ld, int N, int D)
{
    const int b = blockIdx.x;
    const int tid = threadIdx.x;
    const int lane = tid & 63;
    const int wave = tid >> 6;
    __shared__ float sc[64];

    const float* whb = Wh + (size_t)b * 512;
    const int hoff = lane * 8;             // 64 lanes x 8 = 512 exactly
    float wh[8], bb[8], ww[8];
    {
        float4 t0 = *(const float4*)(whb + hoff), t1 = *(const float4*)(whb + hoff + 4);
        wh[0]=t0.x; wh[1]=t0.y; wh[2]=t0.z; wh[3]=t0.w; wh[4]=t1.x; wh[5]=t1.y; wh[6]=t1.z; wh[7]=t1.w;
        t0 = *(const float4*)(bias + hoff); t1 = *(const float4*)(bias + hoff + 4);
        bb[0]=t0.x; bb[1]=t0.y; bb[2]=t0.z; bb[3]=t0.w; bb[4]=t1.x; bb[5]=t1.y; bb[6]=t1.z; bb[7]=t1.w;
        t0 = *(const float4*)(w + hoff); t1 = *(const float4*)(w + hoff + 4);
        ww[0]=t0.x; ww[1]=t0.y; ww[2]=t0.z; ww[3]=t0.w; ww[4]=t1.x; ww[5]=t1.y; ww[6]=t1.z; ww[7]=t1.w;
    }
    for (int n = wave; n < N; n += 4) {
        const short8 u = *(const short8*)(U + ((size_t)b * N + n) * 512 + hoff);
        float s = 0.f;
#pragma unroll
        for (int e = 0; e < 8; ++e)
            s += tanhf(wh[e] + bfbits2f(u[e]) + bb[e]) * ww[e];
#pragma unroll
        for (int off = 32; off > 0; off >>= 1) s += __shfl_down(s, off);
        if (lane == 0) sc[n] = s;
    }
    __syncthreads();
    if (tid == 0) {
        float mx = -3.4e38f;
        for (int n = 0; n < N; ++n) mx = fmaxf(mx, sc[n]);
        float sum = 0.f;
        for (int n = 0; n < N; ++n) { float e = expf(sc[n] - mx); sc[n] = e; sum += e; }
        const float inv = 1.f / sum;
        for (int n = 0; n < N; ++n) sc[n] *= inv;
    }
    __syncthreads();
    for (int d = tid; d < D; d += TPB) {
        float a = 0.f;
        for (int n = 0; n < N; ++n)
            a += sc[n] * feats[((size_t)b * N + n) * feats_ld + d];
        dst[(size_t)b * dst_ld + d] = __float2bfloat16(a);
    }
}

__device__ __forceinline__ float sigmoidf_(float x) { return 1.f / (1.f + expf(-x)); }

__global__ __launch_bounds__(TPB)
void lstm_kernel(const float* __restrict__ gates,
                 const float* __restrict__ b_ih,
                 const float* __restrict__ b_hh,
                 const float* __restrict__ c0,
                 float* __restrict__ out_h,
                 float* __restrict__ out_c,
                 __hip_bfloat16* __restrict__ h_bf)
{
    const int idx = blockIdx.x * TPB + threadIdx.x;   // B*H threads
    if (idx >= 1024 * 512) return;
    const int hh = idx & 511;
    const float* g = gates + (size_t)(idx >> 9) * 2048;
    const float gi = g[hh]        + b_ih[hh]        + b_hh[hh];
    const float gf = g[512 + hh]  + b_ih[512 + hh]  + b_hh[512 + hh];
    const float gg = g[1024 + hh] + b_ih[1024 + hh] + b_hh[1024 + hh];
    const float go = g[1536 + hh] + b_ih[1536 + hh] + b_hh[1536 + hh];
    const float c = sigmoidf_(gf) * c0[idx] + sigmoidf_(gi) * tanhf(gg);
    const float h = sigmoidf_(go) * tanhf(c);
    out_h[idx] = h;
    out_c[idx] = c;
    h_bf[idx]  = __float2bfloat16(h);
}

// ---------------------------------------------------------------------------
// final log-softmax pass: reduce rowpart partials -> lse; row -= lse
// ---------------------------------------------------------------------------
__global__ __launch_bounds__(TPB)
void lsub(float* __restrict__ logits, const float* __restrict__ rowpart,
          int NT, int Mrow, int V)
{
    const int b = blockIdx.y;
    float* row = logits + (size_t)b * V;
    const int tid = threadIdx.x;

    __shared__ float red[TPB];
    float s = 0.f;
    for (int j = tid; j < NT; j += TPB) s += rowpart[(size_t)j * Mrow + b];
    red[tid] = s; __syncthreads();
    for (int st = TPB / 2; st > 0; st >>= 1) {
        if (tid < st) red[tid] += red[tid + st];
        __syncthreads();
    }
    const float lse = logf(red[0]);

    const int mis  = (int)(((uintptr_t)row >> 2) & 3);
    const int head = mis ? 4 - mis : 0;
    const int nv   = (V - head) >> 2;
    const int tail0 = head + nv * 4;
    if (blockIdx.x == 0) {
        if (tid < head) row[tid] -= lse;
        for (int i = tail0 + tid; i < V; i += TPB) row[i] -= lse;
    }
    for (int k = blockIdx.x * TPB + tid; k < nv; k += gridDim.x * TPB) {
        float4 x = *(const float4*)(row + head + 4 * k);
        x.x -= lse; x.y -= lse; x.z -= lse; x.w -= lse;
        *(float4*)(row + head + 4 * k) = x;
    }
}

// ---------------------------------------------------------------------------

extern "C" void kernel_launch(void* const* d_in, const int* in_sizes, int n_in,
                              void* d_out, int out_size, void* d_ws, size_t ws_size,
                              hipStream_t stream)
{
    (void)in_sizes; (void)n_in; (void)out_size;
    const int B = 1024, H = 512, S = 300, E = 512, V = 50257;
    const int NO = 36, NA = 26, NV_ = 26, NOS = 20;
    const int Sp = 320;      // S padded to multiple of 32 (K of semantic U GEMM)
    const int S3p = 928;     // 3*S=900 padded to multiple of 32
    const int NT = (V + 127) / 128;   // 393 logits N-tiles
    const int Vp = NT * 128;          // 50304

    typedef const float* cf;
    cf objects   = (cf)d_in[0];
    cf action    = (cf)d_in[1];
    cf video     = (cf)d_in[2];
    cf obj_sem   = (cf)d_in[3];
    cf act_sem   = (cf)d_in[4];
    cf vid_sem   = (cf)d_in[5];
    cf embed     = (cf)d_in[6];
    cf h0        = (cf)d_in[7];
    cf c0        = (cf)d_in[8];
    cf W_w       = (cf)d_in[9];
    cf Uo_w      = (cf)d_in[10];
    cf bo        = (cf)d_in[11];
    cf wo_w      = (cf)d_in[12];
    cf Uos_w     = (cf)d_in[13];
    cf bos       = (cf)d_in[14];
    cf wos_w     = (cf)d_in[15];
    cf Um_w      = (cf)d_in[16];
    cf bm        = (cf)d_in[17];
    cf wm_w      = (cf)d_in[18];
    cf Uv_w      = (cf)d_in[19];
    cf bv        = (cf)d_in[20];
    cf wv_w      = (cf)d_in[21];
    cf vis_w     = (cf)d_in[22];
    cf vis_b     = (cf)d_in[23];
    cf sem_w     = (cf)d_in[24];
    cf sem_b     = (cf)d_in[25];
    cf W_ih      = (cf)d_in[26];
    cf W_hh      = (cf)d_in[27];
    cf b_ih      = (cf)d_in[28];
    cf b_hh      = (cf)d_in[29];
    cf to_word_w = (cf)d_in[30];
    cf to_word_b = (cf)d_in[31];
    cf logit_w   = (cf)d_in[32];
    cf logit_b   = (cf)d_in[33];

    typedef __hip_bfloat16 bf;
    char* p = (char*)d_ws;
    auto take = [&](size_t bytes) { char* r = p; p += (bytes + 255) & ~(size_t)255; return r; };

    // Mandatory workspace ~52 MiB (proven envelope ~56 MiB).
    float* Wh   = (float*)take((size_t)B * H * 4);           // 2 MiB
    bf* x       = (bf*)take((size_t)B * 2048 * 2);           // [vis|sem|embed|h0]  4 MiB
    bf* xvis    = (bf*)take((size_t)B * 1536 * 2);           // 3 MiB
    bf* xsem    = (bf*)take((size_t)B * S3p * 2);            // 1.81 MiB
    bf* h_bf    = (bf*)take((size_t)B * H * 2);              // 1 MiB
    bf* word    = (bf*)take((size_t)B * E * 2);              // 1 MiB
    // region 36 MiB, time-shared:
    //   [0..36)  U during attn phase
    //   [0..8)   gates (fp32) during LSTM phase
    //   [28..36) Wcat = [W_ih|W_hh] bf16 (converted after last attn)
    char* region = take((size_t)B * NO * H * 2);
    bf* U        = (bf*)region;
    float* gates = (float*)region;
    bf* Wcat     = (bf*)(region + (size_t)28 * 1024 * 1024);
    bf* wsm = (bf*)take((size_t)512 * 1536 * 2);             // 1.5 MiB weight scratch
    float* rowpart = (float*)take((size_t)NT * B * 4);       // 1.61 MiB (no atomics)

    // Optional: bf16 logit_w (fully-async logits GEMM) if workspace permits.
    const size_t lbf_bytes = (size_t)Vp * E * 2;             // 49.1 MiB
    const size_t used = (size_t)(p - (char*)d_ws);
    const bool have_lbf = ws_size >= used + lbf_bytes + 256;
    bf* logit_bf = have_lbf ? (bf*)take(lbf_bytes) : nullptr;

    float* out_logp = (float*)d_out;
    float* out_h = out_logp + (size_t)B * V;
    float* out_c = out_h + (size_t)B * H;

    const dim3 blk(TPB);
    auto g128 = [](int M, int N) { return dim3((unsigned)(N >> 7), (unsigned)(M >> 7)); };
    auto cvt = [&](const float* src, long sld, bf* dst, long dld,
                   int rd, int cd, int rs, int cs) {
        const int total = rd * (cd >> 2);
        cvt2bf<<<(total + TPB - 1) / TPB, blk, 0, stream>>>(src, sld, dst, dld, rd, cd, rs, cs);
    };

    // ---- direct concat fills (fp32 -> bf16, with K-pad zeroing) ----
    cvt(h0, H, x + 1536, 2048, B, H, B, H);                  // h0 -> x[:,1536:2048]
    cvt(embed, E, x + 1024, 2048, B, E, B, E);               // embed -> x[:,1024:1536]
    cvt(act_sem, S, xsem + S, S3p, B, S, B, S);
    cvt(vid_sem, S, xsem + 2 * S, S3p, B, S, B, S);
    cvt(act_sem, S, xsem + 3 * S, S3p, B, S3p - 3 * S, 0, 0); // zeros cols 900..927

    // 1. Wh = h0 @ W_w^T  (fp32 out)
    cvt(W_w, H, wsm, H, H, H, H, H);
    gemm_bf<bf, bf, float, false, false, false, false, false><<<g128(B, H), blk, 0, stream>>>(
        x + 1536, 2048, H, wsm, H, 0, Wh, H, nullptr, H, H, nullptr);

    // 2. objects attention -> xvis[:, 1024:1536]
    cvt(Uo_w, H, wsm, H, H, H, H, H);
    gemm_bf<float, bf, bf, false, false, false, false, false><<<g128(B * NO, H), blk, 0, stream>>>(
        objects, H, H, wsm, H, 0, U, H, nullptr, H, H, nullptr);
    attn_kernel<<<B, blk, 0, stream>>>(Wh, U, objects, H, bo, wo_w, xvis + 2 * H, 1536, NO, H);

    // 3. motion attention -> xvis[:, 512:1024]
    cvt(Um_w, H, wsm, H, H, H, H, H);
    gemm_bf<float, bf, bf, false, false, false, false, false><<<g128(B * NA, H), blk, 0, stream>>>(
        action, H, H, wsm, H, 0, U, H, nullptr, H, H, nullptr);
    attn_kernel<<<B, blk, 0, stream>>>(Wh, U, action, H, bm, wm_w, xvis + H, 1536, NA, H);

    // 4. video attention -> xvis[:, 0:512]
    cvt(Uv_w, H, wsm, H, H, H, H, H);
    gemm_bf<float, bf, bf, false, false, false, false, false><<<g128(B * NV_, H), blk, 0, stream>>>(
        video, H, H, wsm, H, 0, U, H, nullptr, H, H, nullptr);
    attn_kernel<<<B, blk, 0, stream>>>(Wh, U, video, H, bv, wv_w, xvis, 1536, NV_, H);

    // 5. semantic attention -> xsem[:, 0:300]   (K padded 300->320)
    cvt(Uos_w, S, wsm, Sp, H, Sp, H, S);
    gemm_bf<float, bf, bf, false, false, false, false, false><<<g128(B * NOS, H), blk, 0, stream>>>(
        obj_sem, S, S, wsm, Sp, 0, U, H, nullptr, H, Sp, nullptr);
    attn_kernel<<<B, blk, 0, stream>>>(Wh, U, obj_sem, S, bos, wos_w, xsem, S3p, NOS, S);

    // Wcat = [W_ih | W_hh] bf16 (U dead from here; region tail reusable)
    cvt(W_ih, 2 * H + E, Wcat, 2048, 2048, 1536, 2048, 1536);
    cvt(W_hh, H, Wcat + 1536, 2048, 2048, 512, 2048, 512);
    // logit_w -> bf16 once, if workspace allows (pad rows zeroed)
    if (have_lbf) cvt(logit_w, E, logit_bf, E, Vp, E, V, E);

    // 6. visual = xvis @ vis_w^T + vis_b -> x[:, 0:512]
    cvt(vis_w, 3 * H, wsm, 3 * H, H, 3 * H, H, 3 * H);
    gemm_bf<bf, bf, bf, false, true, false, false, false><<<g128(B, H), blk, 0, stream>>>(
        xvis, 1536, 1536, wsm, 1536, 0, x, 2048, vis_b, H, 1536, nullptr);

    // 7. sem = xsem @ sem_w^T + sem_b -> x[:, 512:1024]
    cvt(sem_w, 3 * S, wsm, S3p, H, S3p, H, 3 * S);
    gemm_bf<bf, bf, bf, false, true, false, false, false><<<g128(B, H), blk, 0, stream>>>(
        xsem, S3p, S3p, wsm, S3p, 0, x + H, 2048, sem_b, H, S3p, nullptr);

    // 8. gates = [x|h0] @ [W_ih|W_hh]^T  (single K=2048 GEMM)
    gemm_bf<bf, bf, float, false, false, false, false, false><<<g128(B, 2048), blk, 0, stream>>>(
        x, 2048, 2048, Wcat, 2048, 0, gates, 2048, nullptr, 2048, 2048, nullptr);

    // 9. LSTM pointwise -> out_h, out_c (fp32), h_bf (bf16)
    lstm_kernel<<<(B * H) / TPB, blk, 0, stream>>>(gates, b_ih, b_hh, c0, out_h, out_c, h_bf);

    // 10. word = h @ to_word_w^T + b
    cvt(to_word_w, H, wsm, H, E, H, E, H);
    gemm_bf<bf, bf, bf, false, true, false, false, false><<<g128(B, E), blk, 0, stream>>>(
        h_bf, H, H, wsm, H, 0, word, E, to_word_b, E, H, nullptr);

    // 11. logits = word @ logit_w^T + b; epilogue writes per-row exp-sums to
    //     rowpart (shuffle-reduced, no atomics). SWAPGRID: 8 M-tiles x-fast.
    if (have_lbf) {
        gemm_bf<bf, bf, float, false, true, true, true, true><<<dim3(B / 128, NT), blk, 0, stream>>>(
            word, E, E, logit_bf, E, 0, out_logp, (long)V, logit_b, V, E, rowpart);
    } else {
        gemm_bf<bf, float, float, false, true, true, true, true><<<dim3(B / 128, NT), blk, 0, stream>>>(
            word, E, E, logit_w, E, V, out_logp, (long)V, logit_b, V, E, rowpart);
    }

    // 12. row log-softmax subtract: reduce partials, row -= lse
    lsub<<<dim3(4, B), blk, 0, stream>>>(out_logp, rowpart, NT, B, V);
}